// Round 8
// baseline (253.993 us; speedup 1.0000x reference)
//
#include <hip/hip_runtime.h>
#include <hip/hip_bf16.h>

typedef __hip_bfloat16 bf16;
typedef __attribute__((ext_vector_type(8))) short short8;
typedef __attribute__((ext_vector_type(4))) float floatx4;

#define B_   4
#define C_   256
#define CQ_  32
#define MID_ 16
#define HW_  3136

__device__ __forceinline__ unsigned short f2bf(float f) {
    __hip_bfloat16 h = __float2bfloat16(f);
    return *(unsigned short*)&h;
}
__device__ __forceinline__ float bf2f(short s) {
    return __uint_as_float(((unsigned)(unsigned short)s) << 16);
}

// ====================== K1: kq GEMM + xt interleave + wfp + gpk ======================
// blocks 0..783   : kq GEMM, 16-px tiles  (hw0 = (bid%196)*16, b = bid/196)
// blocks 784..979 : xt[b][cq][px][8m] bf16 interleave (s = bid2%49 -> 64 px, b = bid2/49)
// blocks 980..995 : wfp permute;  block 996: gpk
__global__ void __launch_bounds__(256) k1_kernel(const float* __restrict__ x,
        const float* __restrict__ w_k, const float* __restrict__ b_k,
        const float* __restrict__ w_q, const float* __restrict__ b_q,
        const float* __restrict__ w_f,
        const float* __restrict__ wg1, const float* __restrict__ bg1,
        const float* __restrict__ wg2, const float* __restrict__ bg2,
        short* __restrict__ km, short* __restrict__ qm,
        short* __restrict__ xt, short* __restrict__ wfp, float* __restrict__ gpk) {
    int bid = blockIdx.x, t = threadIdx.x;

    if (bid >= 784) {
        if (bid < 980) {           // ---- xt interleave ----
            int bid2 = bid - 784;
            int s = bid2 % 49, b = bid2 / 49;
            int px = s * 64 + (t & 63);
            int cg = t >> 6;
            const float* xb = x + (size_t)b * C_ * HW_ + px;
            #pragma unroll
            for (int cqi = 0; cqi < 8; cqi++) {
                int cq = cg * 8 + cqi;
                short8 v;
                #pragma unroll
                for (int m = 0; m < 8; m++)
                    v[m] = (short)f2bf(xb[(size_t)(m * CQ_ + cq) * HW_]);
                *(short8*)&xt[(((size_t)b * CQ_ + cq) * HW_ + px) * 8] = v;
            }
        } else if (bid < 996) {    // ---- wfp[ch][kk], kk=cq*8+m <- w_f[ch][m*32+cq] ----
            int base = (bid - 980) * 4096;
            #pragma unroll
            for (int s = 0; s < 16; s++) {
                int j = base + s * 256 + t;
                wfp[j] = (short)f2bf(w_f[(j >> 8) * 256 + (j & 7) * 32 + ((j & 255) >> 3)]);
            }
        } else {                   // ---- geometry prior ----
            for (int idx = t; idx < CQ_ * 49; idx += 256) {
                int cq = idx / 49, ij = idx % 49;
                int i = ij / 7, j = ij % 7;
                float xp = (float)(j - 3), yp = (float)(3 - i);
                float acc = bg2[cq];
                #pragma unroll
                for (int o = 0; o < MID_; o++) {
                    float g1 = wg1[o * 2] * xp + wg1[o * 2 + 1] * yp + bg1[o];
                    acc += wg2[cq * MID_ + o] * fmaxf(g1, 0.f);
                }
                gpk[idx] = acc;
            }
        }
        return;
    }

    // ---- kq GEMM: M=64 (32 km + 32 qm), K=256, N=16 px ----
    __shared__ short lt[16 * 264];   // [px][c] bf16, 16B chunks swizzled
    int hw0 = (bid % 196) * 16;
    int b   = bid / 196;

    int pq = t & 3, cb = t >> 2;                 // px-quad, 4-channel group
    const float* xb = x + (size_t)b * C_ * HW_ + hw0 + pq * 4;
    floatx4 f[4];
    #pragma unroll
    for (int ii = 0; ii < 4; ii++)
        f[ii] = *(const floatx4*)(xb + (size_t)(cb * 4 + ii) * HW_);

    // A-frags: convert this lane's weight row fp32->bf16 (overlaps staging latency)
    int wave = t >> 6, lane = t & 63, quad = lane >> 4, nl = lane & 15;
    int m0 = wave * 16;
    int row = m0 + nl;
    const float* wsrc = (row < 32) ? (w_k + row * C_) : (w_q + (row - 32) * C_);
    short8 af[8];
    #pragma unroll
    for (int k0 = 0; k0 < 8; k0++) {
        floatx4 wa = *(const floatx4*)(wsrc + k0 * 32 + quad * 8);
        floatx4 wb = *(const floatx4*)(wsrc + k0 * 32 + quad * 8 + 4);
        short8 v;
        #pragma unroll
        for (int u = 0; u < 4; u++) { v[u] = (short)f2bf(wa[u]); v[u + 4] = (short)f2bf(wb[u]); }
        af[k0] = v;
    }

    #pragma unroll
    for (int pr = 0; pr < 2; pr++) {             // pack c-pairs -> b32 LDS writes
        int c = cb * 4 + pr * 2;
        int c8 = c >> 3, sub = c & 7;
        #pragma unroll
        for (int u = 0; u < 4; u++) {
            int px = pq * 4 + u;
            unsigned uu = (unsigned)f2bf(f[pr * 2][u]) | ((unsigned)f2bf(f[pr * 2 + 1][u]) << 16);
            *(unsigned*)&lt[px * 264 + ((c8 + pq) & 31) * 8 + sub] = uu;
        }
    }
    __syncthreads();

    floatx4 acc = {0.f, 0.f, 0.f, 0.f};
    int prow = nl * 264, sw = nl >> 2;
    #pragma unroll
    for (int k0 = 0; k0 < 8; k0++) {
        short8 bfr = *(const short8*)&lt[prow + (((k0 * 4 + quad) + sw) & 31) * 8];
        acc = __builtin_amdgcn_mfma_f32_16x16x32_bf16(af[k0], bfr, acc, 0, 0, 0);
    }
    #pragma unroll
    for (int r = 0; r < 4; r++) {
        int ch = m0 + quad * 4 + r;
        bool isK = (ch < 32);
        int c = isK ? ch : ch - 32;
        float bias = isK ? b_k[c] : b_q[c];
        short* dst = (isK ? km : qm) + ((size_t)b * CQ_ + c) * HW_ + hw0 + nl;
        dst[0] = (short)f2bf(acc[r] + bias);
    }
}

// ============ K2: core — chunk-copy staging from xt, 4-wave blocks, all-resident ============
// grid (7 stripes, 32 cq, 4 b) = 896 blocks, 256 thr; threads t<224: 2 output rows each.
__global__ void __launch_bounds__(256, 4) core_kernel(const short* __restrict__ xt,
        const short* __restrict__ km, const short* __restrict__ qm,
        const float* __restrict__ gpk, short* __restrict__ pret) {
    __shared__ float kms[14 * 64];      // [rr][p] fp32
    __shared__ short xs[14 * 64 * 8];   // [rr][p][8m] bf16, 16B chunks

    int ht = blockIdx.x, cq = blockIdx.y, b = blockIdx.z;
    int h0 = ht * 8, t = threadIdx.x;

    const short* kmc = km + ((size_t)b * CQ_ + cq) * HW_;
    const short* xtc = xt + (((size_t)b * CQ_ + cq) * HW_) * 8;

    // stage both tiles: 896 chunk-tasks each (rr 0..13, p 0..63), pure coalesced copies
    for (int u = t; u < 896; u += 256) {
        int rr = u >> 6, p = u & 63;
        int gh = h0 + rr - 3, gw = p - 4;
        bool in = ((unsigned)gh < 56u) && ((unsigned)gw < 56u);
        int o = gh * 56 + gw;
        short8 v = {0,0,0,0,0,0,0,0};
        float kv = 0.f;
        if (in) { v = *(const short8*)&xtc[(size_t)o * 8]; kv = bf2f(kmc[o]); }
        *(short8*)&xs[u * 8] = v;
        kms[u] = kv;
    }
    __syncthreads();

    if (t >= 224) return;
    int rp = t / 56, w = t % 56;
    const float* gp = gpk + cq * 49;    // wave-uniform -> scalar loads

    #pragma unroll
    for (int rowi = 0; rowi < 2; rowi++) {
        int r = rp * 2 + rowi;
        int h = h0 + r;
        float q = bf2f(qm[((size_t)b * CQ_ + cq) * HW_ + h * 56 + w]);

        float acc[8];
        #pragma unroll
        for (int m = 0; m < 8; m++) acc[m] = 0.f;

        #pragma unroll
        for (int i = 0; i < 7; i++) {
            const float* kr = &kms[(r + i) * 64 + w + 1];
            float v[7], s = 0.f;
            #pragma unroll
            for (int j = 0; j < 7; j++) {   // logits bounded: exp safe without max-sub
                v[j] = __expf(kr[j] * q + gp[i * 7 + j]);
                s += v[j];
            }
            float rm[8];
            #pragma unroll
            for (int m = 0; m < 8; m++) rm[m] = 0.f;
            #pragma unroll
            for (int j = 0; j < 7; j++) {
                short8 xv = *(const short8*)&xs[((r + i) * 64 + w + 1 + j) * 8];
                #pragma unroll
                for (int m = 0; m < 8; m++) rm[m] += v[j] * bf2f(xv[m]);
            }
            float inv = 1.0f / s;
            #pragma unroll
            for (int m = 0; m < 8; m++) acc[m] += inv * rm[m];
        }

        short8 o8;
        #pragma unroll
        for (int m = 0; m < 8; m++) o8[m] = (short)f2bf(acc[m]);
        *(short8*)&pret[((size_t)b * HW_ + h * 56 + w) * C_ + cq * 8] = o8;
    }
}

// ============ K3: final 1x1 conv via MFMA, LDS-free (B-frags direct from pre_t) ============
__global__ void __launch_bounds__(256) fconv_mfma(const short* __restrict__ pret,
                                                  const short* __restrict__ wfp,
                                                  const float* __restrict__ b_f,
                                                  float* __restrict__ out) {
    int hw0 = blockIdx.x * 64;
    int bm  = blockIdx.y;
    int b   = blockIdx.z;
    int t   = threadIdx.x, wave = t >> 6, lane = t & 63, quad = lane >> 4, nl = lane & 15;
    int m0  = bm * 64 + wave * 16;

    const short* arow = wfp + (m0 + nl) * C_ + quad * 8;
    short8 af[8];
    #pragma unroll
    for (int k0 = 0; k0 < 8; k0++) af[k0] = *(const short8*)(arow + k0 * 32);

    floatx4 acc[4];
    #pragma unroll
    for (int nt = 0; nt < 4; nt++) acc[nt] = (floatx4){0.f,0.f,0.f,0.f};

    const short* pb = pret + ((size_t)b * HW_ + hw0 + nl) * C_ + quad * 8;
    #pragma unroll
    for (int nt = 0; nt < 4; nt++) {
        const short* bp = pb + (size_t)nt * 16 * C_;
        #pragma unroll
        for (int k0 = 0; k0 < 8; k0++)
            acc[nt] = __builtin_amdgcn_mfma_f32_16x16x32_bf16(af[k0], *(const short8*)(bp + k0 * 32),
                                                              acc[nt], 0, 0, 0);
    }

    #pragma unroll
    for (int r = 0; r < 4; r++) {
        int ch = m0 + quad * 4 + r;
        float bias = b_f[ch];
        float* dst = out + ((size_t)b * C_ + ch) * HW_ + hw0 + nl;
        #pragma unroll
        for (int nt = 0; nt < 4; nt++)
            dst[nt * 16] = acc[nt][r] + bias;
    }
}

extern "C" void kernel_launch(void* const* d_in, const int* in_sizes, int n_in,
                              void* d_out, int out_size, void* d_ws, size_t ws_size,
                              hipStream_t stream) {
    const float* x    = (const float*)d_in[0];
    const float* w_k  = (const float*)d_in[1];
    const float* b_k  = (const float*)d_in[2];
    const float* w_q  = (const float*)d_in[3];
    const float* b_q  = (const float*)d_in[4];
    const float* w_g1 = (const float*)d_in[5];
    const float* b_g1 = (const float*)d_in[6];
    const float* w_g2 = (const float*)d_in[7];
    const float* b_g2 = (const float*)d_in[8];
    const float* w_f  = (const float*)d_in[9];
    const float* b_f  = (const float*)d_in[10];
    float* out = (float*)d_out;

    short* ws   = (short*)d_ws;
    short* km   = ws;                                   // B*CQ*HW
    short* qm   = km  + (size_t)B_ * CQ_ * HW_;         // B*CQ*HW
    short* xt   = qm  + (size_t)B_ * CQ_ * HW_;         // B*CQ*HW*8
    short* wfp  = xt  + (size_t)B_ * CQ_ * HW_ * 8;     // 256*256
    short* pret = wfp + C_ * C_;                        // B*HW*256
    float* gpk  = (float*)(pret + (size_t)B_ * HW_ * C_);  // 1568 f32

    k1_kernel<<<dim3(997), 256, 0, stream>>>(x, w_k, b_k, w_q, b_q, w_f,
                                             w_g1, b_g1, w_g2, b_g2, km, qm, xt, wfp, gpk);
    core_kernel<<<dim3(7, CQ_, B_), 256, 0, stream>>>(xt, km, qm, gpk, pret);
    fconv_mfma<<<dim3(HW_ / 64, C_ / 64, B_), 256, 0, stream>>>(pret, wfp, b_f, out);
}

// Round 9
// 132.337 us; speedup vs baseline: 1.9193x; 1.9193x over previous
//
#include <hip/hip_runtime.h>
#include <hip/hip_bf16.h>

typedef __hip_bfloat16 bf16;
typedef __attribute__((ext_vector_type(8))) short short8;
typedef __attribute__((ext_vector_type(4))) float floatx4;

#define B_   4
#define C_   256
#define CQ_  32
#define MID_ 16
#define HW_  3136

__device__ __forceinline__ unsigned short f2bf(float f) {
    __hip_bfloat16 h = __float2bfloat16(f);
    return *(unsigned short*)&h;
}

// ============ K1: kq GEMM (784 blocks, 16-px tiles) + wfp permute (16) + gpk (1) ============
__global__ void __launch_bounds__(256) kq_setup(const float* __restrict__ x,
        const float* __restrict__ w_k, const float* __restrict__ b_k,
        const float* __restrict__ w_q, const float* __restrict__ b_q,
        const float* __restrict__ w_f,
        const float* __restrict__ wg1, const float* __restrict__ bg1,
        const float* __restrict__ wg2, const float* __restrict__ bg2,
        float* __restrict__ km, float* __restrict__ qm,
        short* __restrict__ wfp, float* __restrict__ gpk) {
    int bid = blockIdx.x, t = threadIdx.x;
    if (bid >= 784) {
        if (bid < 800) {           // wfp[ch][kk], kk=cq*8+m <- w_f[ch][m*32+cq]
            int base = (bid - 784) * 4096;
            #pragma unroll
            for (int s = 0; s < 16; s++) {
                int j = base + s * 256 + t;
                wfp[j] = (short)f2bf(w_f[(j >> 8) * 256 + (j & 7) * 32 + ((j & 255) >> 3)]);
            }
        } else {                   // geometry prior, fp32
            for (int idx = t; idx < CQ_ * 49; idx += 256) {
                int cq = idx / 49, ij = idx % 49;
                int i = ij / 7, j = ij % 7;
                float xp = (float)(j - 3), yp = (float)(3 - i);
                float acc = bg2[cq];
                #pragma unroll
                for (int o = 0; o < MID_; o++) {
                    float g1 = wg1[o * 2] * xp + wg1[o * 2 + 1] * yp + bg1[o];
                    acc += wg2[cq * MID_ + o] * fmaxf(g1, 0.f);
                }
                gpk[idx] = acc;
            }
        }
        return;
    }
    // ---- kq GEMM: M=64 (32 km + 32 qm), K=256, N=16 px ----
    __shared__ short lt[16 * 264];   // [px][c] bf16, 16B chunks swizzled
    int hw0 = (bid % 196) * 16;
    int b   = bid / 196;

    int pq = t & 3, cb = t >> 2;                 // px-quad, 4-channel group
    const float* xb = x + (size_t)b * C_ * HW_ + hw0 + pq * 4;
    floatx4 f[4];
    #pragma unroll
    for (int ii = 0; ii < 4; ii++)
        f[ii] = *(const floatx4*)(xb + (size_t)(cb * 4 + ii) * HW_);

    // A-frags: convert this lane's weight row fp32->bf16 (overlaps staging latency)
    int wave = t >> 6, lane = t & 63, quad = lane >> 4, nl = lane & 15;
    int m0 = wave * 16;
    int row = m0 + nl;
    const float* wsrc = (row < 32) ? (w_k + row * C_) : (w_q + (row - 32) * C_);
    short8 af[8];
    #pragma unroll
    for (int k0 = 0; k0 < 8; k0++) {
        floatx4 wa = *(const floatx4*)(wsrc + k0 * 32 + quad * 8);
        floatx4 wb = *(const floatx4*)(wsrc + k0 * 32 + quad * 8 + 4);
        short8 v;
        #pragma unroll
        for (int u = 0; u < 4; u++) { v[u] = (short)f2bf(wa[u]); v[u + 4] = (short)f2bf(wb[u]); }
        af[k0] = v;
    }

    #pragma unroll
    for (int pr = 0; pr < 2; pr++) {             // pack c-pairs -> b32 LDS writes
        int c = cb * 4 + pr * 2;
        int c8 = c >> 3, sub = c & 7;
        #pragma unroll
        for (int u = 0; u < 4; u++) {
            int px = pq * 4 + u;
            unsigned uu = (unsigned)f2bf(f[pr * 2][u]) | ((unsigned)f2bf(f[pr * 2 + 1][u]) << 16);
            *(unsigned*)&lt[px * 264 + ((c8 + pq) & 31) * 8 + sub] = uu;
        }
    }
    __syncthreads();

    floatx4 acc = {0.f, 0.f, 0.f, 0.f};
    int prow = nl * 264, sw = nl >> 2;
    #pragma unroll
    for (int k0 = 0; k0 < 8; k0++) {
        short8 bfr = *(const short8*)&lt[prow + (((k0 * 4 + quad) + sw) & 31) * 8];
        acc = __builtin_amdgcn_mfma_f32_16x16x32_bf16(af[k0], bfr, acc, 0, 0, 0);
    }
    #pragma unroll
    for (int r = 0; r < 4; r++) {
        int ch = m0 + quad * 4 + r;
        bool isK = (ch < 32);
        int c = isK ? ch : ch - 32;
        float bias = isK ? b_k[c] : b_q[c];
        float* dst = (isK ? km : qm) + ((size_t)b * CQ_ + c) * HW_ + hw0 + nl;
        dst[0] = acc[r] + bias;
    }
}

// ============ K2: core — R5 version (proven) + nontemporal pret stores ============
// grid (7 stripes, 32 cq, 4 b); block 448 = 8 rows x 56 cols.
__global__ void __launch_bounds__(448) core_kernel(const float* __restrict__ x,
        const float* __restrict__ km, const float* __restrict__ qm,
        const float* __restrict__ gpk, short* __restrict__ pret) {
    __shared__ float   kms[14 * 62];
    __shared__ floatx4 xs4[2][14 * 62];   // [g][halo pos]: g=0 -> m 0-3, g=1 -> m 4-7

    int ht = blockIdx.x, cq = blockIdx.y, b = blockIdx.z;
    int h0 = ht * 8, t = threadIdx.x;

    const float* kmc = km + ((size_t)b * CQ_ + cq) * HW_;
    for (int idx = t; idx < 868; idx += 448) {
        int rr = idx / 62, cc = idx % 62;
        int gh = h0 + rr - 3, gw = cc - 3;
        bool in = ((unsigned)gh < 56u) && ((unsigned)gw < 56u);
        int o = gh * 56 + gw;
        kms[idx] = in ? kmc[o] : 0.f;
        #pragma unroll
        for (int g = 0; g < 2; g++) {
            floatx4 v;
            #pragma unroll
            for (int mm = 0; mm < 4; mm++) {
                const float* xc = x + ((size_t)b * C_ + (g * 4 + mm) * CQ_ + cq) * HW_;
                v[mm] = in ? xc[o] : 0.f;
            }
            xs4[g][idx] = v;
        }
    }
    __syncthreads();

    int r = t / 56, w = t % 56, h = h0 + r;
    float q = qm[((size_t)b * CQ_ + cq) * HW_ + h * 56 + w];
    const float* gp = gpk + cq * 49;      // wave-uniform -> scalar loads

    float ck[49];
    #pragma unroll
    for (int i = 0; i < 7; i++) {
        int base = (r + i) * 62 + w;
        float v[7], s = 0.f;
        #pragma unroll
        for (int j = 0; j < 7; j++) {     // logits bounded: exp safe without max-sub
            v[j] = __expf(kms[base + j] * q + gp[i * 7 + j]);
            s += v[j];
        }
        float inv = 1.0f / s;
        #pragma unroll
        for (int j = 0; j < 7; j++) ck[i * 7 + j] = v[j] * inv;
    }

    floatx4 a0 = {0.f,0.f,0.f,0.f}, a1 = {0.f,0.f,0.f,0.f};
    #pragma unroll
    for (int i = 0; i < 7; i++) {
        int base = (r + i) * 62 + w;
        #pragma unroll
        for (int j = 0; j < 7; j++) {
            float c = ck[i * 7 + j];
            a0 += c * xs4[0][base + j];   // ds_read_b128
            a1 += c * xs4[1][base + j];
        }
    }

    short8 o8;
    #pragma unroll
    for (int mm = 0; mm < 4; mm++) {
        o8[mm]     = (short)f2bf(a0[mm]);
        o8[mm + 4] = (short)f2bf(a1[mm]);
    }
    // nontemporal: avoid write-allocate RMW on falsely-shared 512B pixel records
    __builtin_nontemporal_store(o8, (short8*)(pret + ((size_t)b * HW_ + h * 56 + w) * C_ + cq * 8));
}

// ============ K3: final 1x1 conv via MFMA, LDS-free, nontemporal out ============
__global__ void __launch_bounds__(256) fconv_mfma(const short* __restrict__ pret,
                                                  const short* __restrict__ wfp,
                                                  const float* __restrict__ b_f,
                                                  float* __restrict__ out) {
    int hw0 = blockIdx.x * 64;
    int bm  = blockIdx.y;
    int b   = blockIdx.z;
    int t   = threadIdx.x, wave = t >> 6, lane = t & 63, quad = lane >> 4, nl = lane & 15;
    int m0  = bm * 64 + wave * 16;

    const short* arow = wfp + (m0 + nl) * C_ + quad * 8;
    short8 af[8];
    #pragma unroll
    for (int k0 = 0; k0 < 8; k0++) af[k0] = *(const short8*)(arow + k0 * 32);

    floatx4 acc[4];
    #pragma unroll
    for (int nt = 0; nt < 4; nt++) acc[nt] = (floatx4){0.f,0.f,0.f,0.f};

    const short* pb = pret + ((size_t)b * HW_ + hw0 + nl) * C_ + quad * 8;
    #pragma unroll
    for (int nt = 0; nt < 4; nt++) {
        const short* bp = pb + (size_t)nt * 16 * C_;
        #pragma unroll
        for (int k0 = 0; k0 < 8; k0++)
            acc[nt] = __builtin_amdgcn_mfma_f32_16x16x32_bf16(af[k0], *(const short8*)(bp + k0 * 32),
                                                              acc[nt], 0, 0, 0);
    }

    #pragma unroll
    for (int r = 0; r < 4; r++) {
        int ch = m0 + quad * 4 + r;
        float bias = b_f[ch];
        float* dst = out + ((size_t)b * C_ + ch) * HW_ + hw0 + nl;
        #pragma unroll
        for (int nt = 0; nt < 4; nt++)
            __builtin_nontemporal_store(acc[nt][r] + bias, dst + nt * 16);
    }
}

extern "C" void kernel_launch(void* const* d_in, const int* in_sizes, int n_in,
                              void* d_out, int out_size, void* d_ws, size_t ws_size,
                              hipStream_t stream) {
    const float* x    = (const float*)d_in[0];
    const float* w_k  = (const float*)d_in[1];
    const float* b_k  = (const float*)d_in[2];
    const float* w_q  = (const float*)d_in[3];
    const float* b_q  = (const float*)d_in[4];
    const float* w_g1 = (const float*)d_in[5];
    const float* b_g1 = (const float*)d_in[6];
    const float* w_g2 = (const float*)d_in[7];
    const float* b_g2 = (const float*)d_in[8];
    const float* w_f  = (const float*)d_in[9];
    const float* b_f  = (const float*)d_in[10];
    float* out = (float*)d_out;

    float* ws   = (float*)d_ws;
    float* km   = ws;                              // 401408 f32
    float* qm   = km + (size_t)B_ * CQ_ * HW_;     // 401408 f32
    float* gpk  = qm + (size_t)B_ * CQ_ * HW_;     // 1568 f32
    short* wfp  = (short*)(gpk + CQ_ * 49);        // 65536 bf16 (kk-permuted w_f)
    short* pret = wfp + C_ * C_;                   // B*HW*256 bf16, [b][px][kk]

    kq_setup<<<dim3(801), 256, 0, stream>>>(x, w_k, b_k, w_q, b_q, w_f,
                                            w_g1, b_g1, w_g2, b_g2, km, qm, wfp, gpk);
    core_kernel<<<dim3(7, CQ_, B_), 448, 0, stream>>>(x, km, qm, gpk, pret);
    fconv_mfma<<<dim3(HW_ / 64, C_ / 64, B_), 256, 0, stream>>>(pret, wfp, b_f, out);
}

// Round 10
// 130.915 us; speedup vs baseline: 1.9401x; 1.0109x over previous
//
#include <hip/hip_runtime.h>
#include <hip/hip_bf16.h>

typedef __hip_bfloat16 bf16;
typedef __attribute__((ext_vector_type(8))) short short8;
typedef __attribute__((ext_vector_type(4))) float floatx4;

#define B_   4
#define C_   256
#define CQ_  32
#define MID_ 16
#define HW_  3136

__device__ __forceinline__ unsigned short f2bf(float f) {
    __hip_bfloat16 h = __float2bfloat16(f);
    return *(unsigned short*)&h;
}

// ---------------- setup: weight converts + geometry prior ----------------
// blocks 0-63: wkqb[64][256] (rows 0-31 w_k, 32-63 w_q)
// blocks 64-319: wfp[ch][kk], kk=cq*8+m <- w_f[ch][m*32+cq]
// blocks 320-326: gpk[cq][i][j] fp32
__global__ void setup_kernel(const float* __restrict__ wk, const float* __restrict__ wq,
                             const float* __restrict__ wf,
                             const float* __restrict__ wg1, const float* __restrict__ bg1,
                             const float* __restrict__ wg2, const float* __restrict__ bg2,
                             short* __restrict__ wkqb, short* __restrict__ wfp,
                             float* __restrict__ gpk) {
    int bid = blockIdx.x, t = threadIdx.x;
    if (bid < 64) {
        int i = bid * 256 + t;
        wkqb[i] = (short)f2bf(i < 8192 ? wk[i] : wq[i - 8192]);
    } else if (bid < 320) {
        int j = (bid - 64) * 256 + t;
        wfp[j] = (short)f2bf(wf[(j >> 8) * 256 + (j & 7) * 32 + ((j & 255) >> 3)]);
    } else {
        int idx = (bid - 320) * 256 + t;
        if (idx >= CQ_ * 49) return;
        int cq = idx / 49, ij = idx % 49;
        int i = ij / 7, j = ij % 7;
        float xp = (float)(j - 3), yp = (float)(3 - i);
        float acc = bg2[cq];
        #pragma unroll
        for (int o = 0; o < MID_; o++) {
            float g1 = wg1[o * 2] * xp + wg1[o * 2 + 1] * yp + bg1[o];
            acc += wg2[cq * MID_ + o] * fmaxf(g1, 0.f);
        }
        gpk[idx] = acc;
    }
}

// ---------------- km/qm via MFMA: 512 thr = 8 waves, 32-px tiles ----------------
// grid (HW/32, B). Staging: each thread 4 hoisted float4 loads. MFMA: wave w ->
// m-tile (w&3), px-half (w>>2).
__global__ void __launch_bounds__(512) kq_mfma(const float* __restrict__ x,
                                               const short* __restrict__ wkqb,
                                               const float* __restrict__ b_k,
                                               const float* __restrict__ b_q,
                                               float* __restrict__ km, float* __restrict__ qm) {
    __shared__ short lt[32 * 264];   // [px][c] bf16, 16B chunks swizzled
    int hw0 = blockIdx.x * 32;
    int b   = blockIdx.y;
    int t   = threadIdx.x;

    // stage x[b][*][hw0..hw0+31]: coalesced float4, hoisted
    int pq = t & 7, cb = t >> 3;                 // px-quad 0-7, c-pair 0-63
    const float* xb = x + (size_t)b * C_ * HW_ + hw0 + pq * 4;
    floatx4 fa[2], fb[2];
    #pragma unroll
    for (int ii = 0; ii < 2; ii++) {
        int c = ii * 128 + cb * 2;
        fa[ii] = *(const floatx4*)(xb + (size_t)c * HW_);
        fb[ii] = *(const floatx4*)(xb + (size_t)(c + 1) * HW_);
    }

    // A-frags from pre-converted bf16 weights (L2-hot)
    int wave = t >> 6, lane = t & 63, quad = lane >> 4, nl = lane & 15;
    int m0 = (wave & 3) * 16;
    int nt = wave >> 2;
    const short* arow = wkqb + (m0 + nl) * C_ + quad * 8;
    short8 af[8];
    #pragma unroll
    for (int k0 = 0; k0 < 8; k0++) af[k0] = *(const short8*)(arow + k0 * 32);

    #pragma unroll
    for (int ii = 0; ii < 2; ii++) {
        int c = ii * 128 + cb * 2;
        int c8 = c >> 3, sub = c & 7;
        #pragma unroll
        for (int u = 0; u < 4; u++) {
            int px = pq * 4 + u;
            unsigned uu = (unsigned)f2bf(fa[ii][u]) | ((unsigned)f2bf(fb[ii][u]) << 16);
            *(unsigned*)&lt[px * 264 + ((c8 + (px >> 2)) & 31) * 8 + sub] = uu;
        }
    }
    __syncthreads();

    int px = nt * 16 + nl;
    int prow = px * 264, sw = px >> 2;
    floatx4 acc = {0.f, 0.f, 0.f, 0.f};
    #pragma unroll
    for (int k0 = 0; k0 < 8; k0++) {
        short8 bfr = *(const short8*)&lt[prow + (((k0 * 4 + quad) + sw) & 31) * 8];
        acc = __builtin_amdgcn_mfma_f32_16x16x32_bf16(af[k0], bfr, acc, 0, 0, 0);
    }
    #pragma unroll
    for (int r = 0; r < 4; r++) {
        int ch = m0 + quad * 4 + r;
        bool isK = (ch < 32);
        int c = isK ? ch : ch - 32;
        float bias = isK ? b_k[c] : b_q[c];
        float* dst = (isK ? km : qm) + ((size_t)b * CQ_ + c) * HW_ + hw0 + px;
        dst[0] = acc[r] + bias;
    }
}

// ---------------- core: R5 staging + rm-reassociated softmax (no ck[49]) ----------------
// grid (7 stripes, 32 cq, 4 b); block 448 = 8 rows x 56 cols.
__global__ void __launch_bounds__(448) core_kernel(const float* __restrict__ x,
        const float* __restrict__ km, const float* __restrict__ qm,
        const float* __restrict__ gpk, short* __restrict__ pret) {
    __shared__ float   kms[14 * 62];
    __shared__ floatx4 xs4[2][14 * 62];   // [g][halo pos]: g=0 -> m 0-3, g=1 -> m 4-7

    int ht = blockIdx.x, cq = blockIdx.y, b = blockIdx.z;
    int h0 = ht * 8, t = threadIdx.x;

    const float* kmc = km + ((size_t)b * CQ_ + cq) * HW_;
    for (int idx = t; idx < 868; idx += 448) {
        int rr = idx / 62, cc = idx % 62;
        int gh = h0 + rr - 3, gw = cc - 3;
        bool in = ((unsigned)gh < 56u) && ((unsigned)gw < 56u);
        int o = gh * 56 + gw;
        kms[idx] = in ? kmc[o] : 0.f;
        #pragma unroll
        for (int g = 0; g < 2; g++) {
            floatx4 v;
            #pragma unroll
            for (int mm = 0; mm < 4; mm++) {
                const float* xc = x + ((size_t)b * C_ + (g * 4 + mm) * CQ_ + cq) * HW_;
                v[mm] = in ? xc[o] : 0.f;
            }
            xs4[g][idx] = v;
        }
    }
    __syncthreads();

    int r = t / 56, w = t % 56, h = h0 + r;
    float q = qm[((size_t)b * CQ_ + cq) * HW_ + h * 56 + w];
    const float* gp = gpk + cq * 49;      // wave-uniform -> scalar loads

    floatx4 a0 = {0.f,0.f,0.f,0.f}, a1 = {0.f,0.f,0.f,0.f};
    #pragma unroll
    for (int i = 0; i < 7; i++) {
        int base = (r + i) * 62 + w;
        float v[7], s = 0.f;
        #pragma unroll
        for (int j = 0; j < 7; j++) {     // logits bounded: exp safe without max-sub
            v[j] = __expf(kms[base + j] * q + gp[i * 7 + j]);
            s += v[j];
        }
        floatx4 r0 = {0.f,0.f,0.f,0.f}, r1 = {0.f,0.f,0.f,0.f};
        #pragma unroll
        for (int j = 0; j < 7; j++) {
            float c = v[j];
            r0 += c * xs4[0][base + j];   // ds_read_b128
            r1 += c * xs4[1][base + j];
        }
        float inv = 1.0f / s;
        a0 += inv * r0;
        a1 += inv * r1;
    }

    short8 o8;
    #pragma unroll
    for (int mm = 0; mm < 4; mm++) {
        o8[mm]     = (short)f2bf(a0[mm]);
        o8[mm + 4] = (short)f2bf(a1[mm]);
    }
    // nontemporal: avoid write-allocate RMW on falsely-shared 512B pixel records
    __builtin_nontemporal_store(o8, (short8*)(pret + ((size_t)b * HW_ + h * 56 + w) * C_ + cq * 8));
}

// ---------------- final 1x1 conv via MFMA, LDS-free ----------------
__global__ void __launch_bounds__(256) fconv_mfma(const short* __restrict__ pret,
                                                  const short* __restrict__ wfp,
                                                  const float* __restrict__ b_f,
                                                  float* __restrict__ out) {
    int hw0 = blockIdx.x * 64;
    int bm  = blockIdx.y;
    int b   = blockIdx.z;
    int t   = threadIdx.x, wave = t >> 6, lane = t & 63, quad = lane >> 4, nl = lane & 15;
    int m0  = bm * 64 + wave * 16;

    const short* arow = wfp + (m0 + nl) * C_ + quad * 8;
    short8 af[8];
    #pragma unroll
    for (int k0 = 0; k0 < 8; k0++) af[k0] = *(const short8*)(arow + k0 * 32);

    floatx4 acc[4];
    #pragma unroll
    for (int nt = 0; nt < 4; nt++) acc[nt] = (floatx4){0.f,0.f,0.f,0.f};

    const short* pb = pret + ((size_t)b * HW_ + hw0 + nl) * C_ + quad * 8;
    #pragma unroll
    for (int nt = 0; nt < 4; nt++) {
        const short* bp = pb + (size_t)nt * 16 * C_;
        #pragma unroll
        for (int k0 = 0; k0 < 8; k0++)
            acc[nt] = __builtin_amdgcn_mfma_f32_16x16x32_bf16(af[k0], *(const short8*)(bp + k0 * 32),
                                                              acc[nt], 0, 0, 0);
    }

    #pragma unroll
    for (int r = 0; r < 4; r++) {
        int ch = m0 + quad * 4 + r;
        float bias = b_f[ch];
        float* dst = out + ((size_t)b * C_ + ch) * HW_ + hw0 + nl;
        #pragma unroll
        for (int nt = 0; nt < 4; nt++)
            dst[nt * 16] = acc[nt][r] + bias;
    }
}

extern "C" void kernel_launch(void* const* d_in, const int* in_sizes, int n_in,
                              void* d_out, int out_size, void* d_ws, size_t ws_size,
                              hipStream_t stream) {
    const float* x    = (const float*)d_in[0];
    const float* w_k  = (const float*)d_in[1];
    const float* b_k  = (const float*)d_in[2];
    const float* w_q  = (const float*)d_in[3];
    const float* b_q  = (const float*)d_in[4];
    const float* w_g1 = (const float*)d_in[5];
    const float* b_g1 = (const float*)d_in[6];
    const float* w_g2 = (const float*)d_in[7];
    const float* b_g2 = (const float*)d_in[8];
    const float* w_f  = (const float*)d_in[9];
    const float* b_f  = (const float*)d_in[10];
    float* out = (float*)d_out;

    float* ws   = (float*)d_ws;
    float* km   = ws;                              // 401408 f32
    float* qm   = km + (size_t)B_ * CQ_ * HW_;     // 401408 f32
    float* gpk  = qm + (size_t)B_ * CQ_ * HW_;     // 1568 f32
    short* wkqb = (short*)(gpk + CQ_ * 49);        // 64*256 bf16
    short* wfp  = wkqb + 64 * C_;                  // 256*256 bf16 (kk-permuted w_f)
    short* pret = wfp + C_ * C_;                   // B*HW*256 bf16, [b][px][kk]

    setup_kernel<<<dim3(327), 256, 0, stream>>>(w_k, w_q, w_f, w_g1, b_g1, w_g2, b_g2,
                                                wkqb, wfp, gpk);
    kq_mfma<<<dim3(HW_ / 32, B_), 512, 0, stream>>>(x, wkqb, b_k, b_q, km, qm);
    core_kernel<<<dim3(7, CQ_, B_), 448, 0, stream>>>(x, km, qm, gpk, pret);
    fconv_mfma<<<dim3(HW_ / 64, C_ / 64, B_), 256, 0, stream>>>(pret, wfp, b_f, out);
}